// Round 12
// baseline (341.462 us; speedup 1.0000x reference)
//
#include <hip/hip_runtime.h>
#include <hip/hip_fp16.h>
#include <math.h>

#define N_NODES 50000
#define E_RAW_N 800000
#define E_TOT   (E_RAW_N + N_NODES)   // 850000 (self-loops appended)
#define NGRAPH  256
#define POOL_F  448                    // 64 + 128 + 256
#define SCAN_B  196                    // ceil(N_NODES / 256)
#define NSLICE  4                      // bnstats partial slices

using f16x8 = __attribute__((ext_vector_type(8))) _Float16;
using f32x4 = __attribute__((ext_vector_type(4))) float;

// ---------------- W transpose helper (fp16 WT[F][K]) ----------------

template<int K, int F>
__device__ void do_wt(const float* __restrict__ W, __half* __restrict__ WT, int blk) {
    int i = blk * 256 + threadIdx.x;
    if (i >= F * (K / 8)) return;
    int f = i / (K / 8);
    int kb = (i % (K / 8)) * 8;
    __half tmp[8];
#pragma unroll
    for (int j = 0; j < 8; ++j) tmp[j] = __float2half(W[(size_t)(kb + j) * F + f]);
    *reinterpret_cast<uint4*>(WT + (size_t)f * K + kb) = *reinterpret_cast<uint4*>(tmp);
}

// ---------------- init + weight transpose (one dispatch) ----------------

__global__ void k_init(int* __restrict__ deg, int* __restrict__ cursor,
                       float* __restrict__ p, float* __restrict__ bn,
                       const float* __restrict__ W1, const float* __restrict__ W2,
                       const float* __restrict__ W3, __half* __restrict__ WT1,
                       __half* __restrict__ WT2, __half* __restrict__ WT3) {
    int b = blockIdx.x;
    if (b < 448) {
        int i = b * 256 + threadIdx.x;
        if (i < N_NODES) { deg[i] = 0; cursor[i] = 0; }
        if (i < NGRAPH * POOL_F) p[i] = 0.f;
        if (i < NSLICE * 512 * 3) bn[i] = 0.f;
    } else {
        int wb = b - 448;
        if (wb < 4)       do_wt<128, 64>(W1, WT1, wb);
        else if (wb < 8)  do_wt<64, 128>(W2, WT2, wb - 4);
        else              do_wt<128, 256>(W3, WT3, wb - 8);
    }
}

// ---------------- CSR build: 4 edges per thread (atomic ILP) ----------------

__global__ void k_deg(const int* __restrict__ dst_raw, int* __restrict__ deg) {
    int t = blockIdx.x * blockDim.x + threadIdx.x;
    int e0 = t * 4;
    if (e0 >= E_TOT) return;
    int4 d4;
    if (e0 < E_RAW_N) {            // E_RAW_N % 4 == 0: group entirely raw
        d4 = *reinterpret_cast<const int4*>(dst_raw + e0);
    } else {
        int b = e0 - E_RAW_N;
        d4 = make_int4(b, b + 1, b + 2, b + 3);
    }
    atomicAdd(&deg[d4.x], 1);
    atomicAdd(&deg[d4.y], 1);
    atomicAdd(&deg[d4.z], 1);
    atomicAdd(&deg[d4.w], 1);
}

__global__ void k_scan1(const int* __restrict__ deg, int* __restrict__ bsum) {
    __shared__ int red[256];
    int i = blockIdx.x * 256 + threadIdx.x;
    int v = (i < N_NODES) ? deg[i] : 0;
    red[threadIdx.x] = v;
    __syncthreads();
    for (int o = 128; o > 0; o >>= 1) {
        if (threadIdx.x < o) red[threadIdx.x] += red[threadIdx.x + o];
        __syncthreads();
    }
    if (threadIdx.x == 0) bsum[blockIdx.x] = red[0];
}

__global__ void k_scan3(const int* __restrict__ deg, const int* __restrict__ bsum,
                        int* __restrict__ rowstart) {
    __shared__ int pre[256];
    __shared__ int s[256];
    int tid = threadIdx.x;
    pre[tid] = (tid < (int)blockIdx.x) ? bsum[tid] : 0;
    int i = blockIdx.x * 256 + tid;
    int v = (i < N_NODES) ? deg[i] : 0;
    s[tid] = v;
    __syncthreads();
    for (int o = 128; o > 0; o >>= 1) {
        if (tid < o) pre[tid] += pre[tid + o];
        __syncthreads();
    }
    for (int o = 1; o < 256; o <<= 1) {
        int t = (tid >= o) ? s[tid - o] : 0;
        __syncthreads();
        s[tid] += t;
        __syncthreads();
    }
    if (i < N_NODES) rowstart[i] = pre[0] + s[tid] - v;
    if (i == 0) rowstart[N_NODES] = E_TOT;
}

__global__ void k_fill(const int* __restrict__ ei, const int* __restrict__ rowstart,
                       int* __restrict__ cursor, int* __restrict__ adj) {
    int t = blockIdx.x * blockDim.x + threadIdx.x;
    int e0 = t * 4;
    if (e0 >= E_TOT) return;
    int4 s4, d4;
    if (e0 < E_RAW_N) {
        s4 = *reinterpret_cast<const int4*>(ei + e0);
        d4 = *reinterpret_cast<const int4*>(ei + E_RAW_N + e0);
    } else {
        int b = e0 - E_RAW_N;
        s4 = make_int4(b, b + 1, b + 2, b + 3);
        d4 = s4;
    }
    int r0 = rowstart[d4.x], r1 = rowstart[d4.y], r2 = rowstart[d4.z], r3 = rowstart[d4.w];
    int c0 = atomicAdd(&cursor[d4.x], 1);
    int c1 = atomicAdd(&cursor[d4.y], 1);
    int c2 = atomicAdd(&cursor[d4.z], 1);
    int c3 = atomicAdd(&cursor[d4.w], 1);
    adj[r0 + c0] = s4.x;
    adj[r1 + c1] = s4.y;
    adj[r2 + c2] = s4.z;
    adj[r3 + c3] = s4.w;
}

// ---------------- MFMA GEMM: h = act(x) @ W, + al epilogue ----------------

template<int K, int F, bool BNIN, typename TIN, typename TOUT>
__global__ void __launch_bounds__(256) k_mfma(
        const TIN* __restrict__ x, const __half* __restrict__ WT,
        const float* __restrict__ bnP,
        const float* __restrict__ g, const float* __restrict__ be,
        const float* __restrict__ a_src, const float* __restrict__ a_dst,
        void* __restrict__ hout, float* __restrict__ al_s, float* __restrict__ al_d) {
    constexpr int NF = F / 16;
    constexpr int KS = K / 32;
    constexpr int MT = 2;
    __shared__ float scs[K], bbs[K];
    int tid = threadIdx.x;
    if constexpr (BNIN) {
        const float invN = 1.f / (float)N_NODES;
        for (int i = tid; i < K; i += 256) {
            float sm = 0.f, sq = 0.f;
#pragma unroll
            for (int s = 0; s < NSLICE; ++s) {
                sm += bnP[s * 2 * K + i];
                sq += bnP[s * 2 * K + K + i];
            }
            float mean = sm * invN;
            float var  = sq * invN - mean * mean;
            float sc = rsqrtf(var + 1e-5f) * g[i];
            scs[i] = sc;
            bbs[i] = be[i] - mean * sc;
        }
        __syncthreads();
    }
    int wave = tid >> 6, lane = tid & 63;
    int col = lane & 15;
    int kg  = lane >> 4;
    long n_base = ((long)blockIdx.x * 4 + wave) * (MT * 16);
    if (n_base >= N_NODES) return;

    bool mv[MT];
#pragma unroll
    for (int m = 0; m < MT; ++m) mv[m] = (n_base + m * 16) < N_NODES;

    f32x4 acc[MT][NF];
#pragma unroll
    for (int m = 0; m < MT; ++m)
#pragma unroll
        for (int t = 0; t < NF; ++t) acc[m][t] = (f32x4){0.f, 0.f, 0.f, 0.f};

    for (int ks = 0; ks < KS; ++ks) {
        int kb = ks * 32 + kg * 8;
        f16x8 af[MT];
#pragma unroll
        for (int m = 0; m < MT; ++m) {
            if (!mv[m]) { af[m] = (f16x8){}; continue; }
            long nrow = n_base + m * 16 + col;
            if constexpr (sizeof(TIN) == 2) {
                uint4 u = *reinterpret_cast<const uint4*>((const __half*)x + nrow * K + kb);
                if constexpr (BNIN) {
                    const __half* hp = reinterpret_cast<const __half*>(&u);
                    f16x8 a;
#pragma unroll
                    for (int j = 0; j < 8; ++j) {
                        float y = __half2float(hp[j]) * scs[kb + j] + bbs[kb + j];
                        y = y > 0.f ? y : 0.01f * y;
                        a[j] = (_Float16)y;
                    }
                    af[m] = a;
                } else {
                    af[m] = *reinterpret_cast<const f16x8*>(&u);
                }
            } else {
                const float* xp = (const float*)x + nrow * K + kb;
                float4 v0 = *reinterpret_cast<const float4*>(xp);
                float4 v1 = *reinterpret_cast<const float4*>(xp + 4);
                f16x8 a;
                a[0] = (_Float16)v0.x; a[1] = (_Float16)v0.y;
                a[2] = (_Float16)v0.z; a[3] = (_Float16)v0.w;
                a[4] = (_Float16)v1.x; a[5] = (_Float16)v1.y;
                a[6] = (_Float16)v1.z; a[7] = (_Float16)v1.w;
                af[m] = a;
            }
        }
#pragma unroll
        for (int t = 0; t < NF; ++t) {
            f16x8 bf = *reinterpret_cast<const f16x8*>(WT + (size_t)(t * 16 + col) * K + kb);
            acc[0][t] = __builtin_amdgcn_mfma_f32_16x16x32_f16(af[0], bf, acc[0][t], 0, 0, 0);
            if constexpr (MT > 1)
                acc[1][t] = __builtin_amdgcn_mfma_f32_16x16x32_f16(af[1], bf, acc[1][t], 0, 0, 0);
        }
    }

#pragma unroll
    for (int m = 0; m < MT; ++m) {
        if (!mv[m]) continue;
#pragma unroll
        for (int t = 0; t < NF; ++t) {
#pragma unroll
            for (int r = 0; r < 4; ++r) {
                long n = n_base + m * 16 + kg * 4 + r;
                float v = acc[m][t][r];
                if constexpr (sizeof(TOUT) == 1) {
                    int pk = __builtin_amdgcn_cvt_pk_fp8_f32(v, v, 0, false);
                    reinterpret_cast<unsigned char*>(hout)[n * F + t * 16 + col] =
                        (unsigned char)(pk & 0xff);
                } else {
                    reinterpret_cast<__half*>(hout)[n * F + t * 16 + col] = __float2half(v);
                }
            }
        }
#pragma unroll
        for (int r = 0; r < 4; ++r) {
            float ss0 = 0.f, sd0 = 0.f, ss1 = 0.f, sd1 = 0.f;
#pragma unroll
            for (int t = 0; t < NF; ++t) {
                float v = acc[m][t][r];
                float as = a_src[t * 16 + col];
                float ad = a_dst[t * 16 + col];
                if (t < NF / 2) { ss0 += v * as; sd0 += v * ad; }
                else            { ss1 += v * as; sd1 += v * ad; }
            }
#pragma unroll
            for (int o = 1; o < 16; o <<= 1) {
                ss0 += __shfl_xor(ss0, o); sd0 += __shfl_xor(sd0, o);
                ss1 += __shfl_xor(ss1, o); sd1 += __shfl_xor(sd1, o);
            }
            if (col == 0) {
                long n = n_base + m * 16 + kg * 4 + r;
                al_s[n * 2]     = ss0; al_s[n * 2 + 1] = ss1;
                al_d[n * 2]     = sd0; al_d[n * 2 + 1] = sd1;
            }
        }
    }
}

// ---------------- per-dst gather: masked wide steps + adj prefetch ----------
// All payload/logit offsets are 32-bit (power-of-two row strides).

template<bool FP8> struct PayT;
template<> struct PayT<false> { using T = uint4; };
template<> struct PayT<true>  { using T = uint2; };

template<bool FP8>
__device__ inline void accum8(typename PayT<FP8>::T u, float ee, float acc[8]) {
    if constexpr (FP8) {
        auto f0 = __builtin_amdgcn_cvt_pk_f32_fp8(u.x, false);
        auto f1 = __builtin_amdgcn_cvt_pk_f32_fp8(u.x, true);
        auto f2 = __builtin_amdgcn_cvt_pk_f32_fp8(u.y, false);
        auto f3 = __builtin_amdgcn_cvt_pk_f32_fp8(u.y, true);
        acc[0] += ee * f0[0]; acc[1] += ee * f0[1];
        acc[2] += ee * f1[0]; acc[3] += ee * f1[1];
        acc[4] += ee * f2[0]; acc[5] += ee * f2[1];
        acc[6] += ee * f3[0]; acc[7] += ee * f3[1];
    } else {
        float2 f0 = __half22float2(*reinterpret_cast<const __half2*>(&u.x));
        float2 f1 = __half22float2(*reinterpret_cast<const __half2*>(&u.y));
        float2 f2 = __half22float2(*reinterpret_cast<const __half2*>(&u.z));
        float2 f3 = __half22float2(*reinterpret_cast<const __half2*>(&u.w));
        acc[0] += ee * f0.x; acc[1] += ee * f0.y;
        acc[2] += ee * f1.x; acc[3] += ee * f1.y;
        acc[4] += ee * f2.x; acc[5] += ee * f2.y;
        acc[6] += ee * f3.x; acc[7] += ee * f3.y;
    }
}

template<int F, int C, bool FP8>
__global__ void __launch_bounds__(256) k_gather(
        const int* __restrict__ rowstart, const int* __restrict__ adj,
        const void* __restrict__ hv, const float* __restrict__ al_s,
        const float* __restrict__ al_d, const float* __restrict__ bias,
        __half* __restrict__ xpre) {
    using LT = typename PayT<FP8>::T;
    constexpr int HPL = 8;                    // features per lane
    constexpr int LPE = F / HPL;              // lanes per edge
    constexpr int EPI = 64 / LPE;             // edge slots per step: 8/4/2
    constexpr int UNR = (EPI >= 8) ? 4 : (16 / EPI);  // 4/4/8
    constexpr int STEP = UNR * EPI;           // 32/16/16 edges per step
    constexpr unsigned RSH = FP8 ? 8 : ((F == 64) ? 7 : 8);  // log2(F*EB)
    int wave = (blockIdx.x * 256 + threadIdx.x) >> 6;
    int lane = threadIdx.x & 63;
    if (wave >= N_NODES) return;
    int n = wave;
    int rs = rowstart[n], re = rowstart[n + 1];
    float2 aldv = *reinterpret_cast<const float2*>(al_d + n * 2);

    const int es = lane / LPE;
    const int fl = lane % LPE;
    const unsigned fi = fl * HPL;
    const int hd = (fi >= C) ? 1 : 0;
    const float alh = hd ? aldv.y : aldv.x;
    const char* base = (const char*)hv;
    const char* alsb = (const char*)al_s;
    const unsigned fioff = FP8 ? fi : fi * 2;

    float acc[HPL];
#pragma unroll
    for (int j = 0; j < HPL; ++j) acc[j] = 0.f;
    float seh = 0.f;

    int nsteps = (re - rs + STEP - 1) / STEP;
    unsigned sN[UNR];
#pragma unroll
    for (int u = 0; u < UNR; ++u) {
        int e = rs + u * EPI + es;
        sN[u] = (unsigned)adj[min(e, re - 1)];
    }
    for (int t = 0; t < nsteps; ++t) {
        int ibase = rs + t * STEP;
        unsigned sC[UNR];
#pragma unroll
        for (int u = 0; u < UNR; ++u) sC[u] = sN[u];
        if (t + 1 < nsteps) {
            int nb = ibase + STEP;
#pragma unroll
            for (int u = 0; u < UNR; ++u) {
                int e = nb + u * EPI + es;
                sN[u] = (unsigned)adj[min(e, re - 1)];
            }
        }
        float alsN[UNR];
        LT hvN[UNR];
#pragma unroll
        for (int u = 0; u < UNR; ++u) {
            alsN[u] = *reinterpret_cast<const float*>(alsb + ((sC[u] << 3) | (unsigned)(hd << 2)));
            hvN[u] = *reinterpret_cast<const LT*>(base + ((sC[u] << RSH) + fioff));
        }
#pragma unroll
        for (int u = 0; u < UNR; ++u) {
            bool valid = (ibase + u * EPI + es) < re;
            float v = alsN[u] + alh; v = v > 0.f ? v : 0.2f * v;
            v = fminf(v, 80.f);
            float ee = valid ? __expf(v) : 0.f;
            seh += ee;
            accum8<FP8>(hvN[u], ee, acc);
        }
    }

#pragma unroll
    for (int o = LPE; o < 64; o <<= 1) {
        seh += __shfl_xor(seh, o);
#pragma unroll
        for (int j = 0; j < HPL; ++j) acc[j] += __shfl_xor(acc[j], o);
    }

    if (es == 0) {
        float inv = 1.f / (seh + 1e-16f);
        const float* bp = bias + fi;
        __half2 o0 = __floats2half2_rn(acc[0] * inv + bp[0], acc[1] * inv + bp[1]);
        __half2 o1 = __floats2half2_rn(acc[2] * inv + bp[2], acc[3] * inv + bp[3]);
        __half2 o2 = __floats2half2_rn(acc[4] * inv + bp[4], acc[5] * inv + bp[5]);
        __half2 o3 = __floats2half2_rn(acc[6] * inv + bp[6], acc[7] * inv + bp[7]);
        uint4 u;
        u.x = *reinterpret_cast<unsigned int*>(&o0);
        u.y = *reinterpret_cast<unsigned int*>(&o1);
        u.z = *reinterpret_cast<unsigned int*>(&o2);
        u.w = *reinterpret_cast<unsigned int*>(&o3);
        *reinterpret_cast<uint4*>(xpre + (size_t)n * F + fi) = u;
    }
}

// ---------------- BatchNorm stats: 4-slice partials, 480 blocks ------------

template<int F>
__global__ void __launch_bounds__(256) k_bnstats(const __half* __restrict__ x,
        float* __restrict__ bnP) {
    constexpr int SLOTS = F / 8;
    constexpr int RPI   = 256 / SLOTS;
    __shared__ float ls[256][8];
    int tid = threadIdx.x;
    int slot = tid % SLOTS;
    int r0 = tid / SLOTS;
    int slice = blockIdx.x & (NSLICE - 1);
    float s[8], q[8];
#pragma unroll
    for (int j = 0; j < 8; ++j) { s[j] = 0.f; q[j] = 0.f; }
    int stride = gridDim.x * RPI;
    for (int n = blockIdx.x * RPI + r0; n < N_NODES; n += stride) {
        uint4 u = *reinterpret_cast<const uint4*>(x + (size_t)n * F + slot * 8);
        float2 f0 = __half22float2(*reinterpret_cast<__half2*>(&u.x));
        float2 f1 = __half22float2(*reinterpret_cast<__half2*>(&u.y));
        float2 f2 = __half22float2(*reinterpret_cast<__half2*>(&u.z));
        float2 f3 = __half22float2(*reinterpret_cast<__half2*>(&u.w));
        float v[8] = {f0.x, f0.y, f1.x, f1.y, f2.x, f2.y, f3.x, f3.y};
#pragma unroll
        for (int j = 0; j < 8; ++j) { s[j] += v[j]; q[j] += v[j] * v[j]; }
    }
#pragma unroll
    for (int j = 0; j < 8; ++j) ls[tid][j] = s[j];
    __syncthreads();
    if (tid < F) {
        int sl = tid / 8, j = tid % 8;
        float t = 0.f;
        for (int r = 0; r < RPI; ++r) t += ls[r * SLOTS + sl][j];
        atomicAdd(&bnP[slice * 2 * F + tid], t);
    }
    __syncthreads();
#pragma unroll
    for (int j = 0; j < 8; ++j) ls[tid][j] = q[j];
    __syncthreads();
    if (tid < F) {
        int sl = tid / 8, j = tid % 8;
        float t = 0.f;
        for (int r = 0; r < RPI; ++r) t += ls[r * SLOTS + sl][j];
        atomicAdd(&bnP[slice * 2 * F + F + tid], t);
    }
}

// ---------------- BN + leaky + pooled-sum only (sorted batch) ----------------

template<int F>
__global__ void k_bnpool(const __half* __restrict__ x, const float* __restrict__ bnP,
                         const float* __restrict__ g,
                         const float* __restrict__ be, const int* __restrict__ batch,
                         float* __restrict__ p, int poff) {
    constexpr int F2 = F / 2;
    constexpr int NGRP = 512 / F;
    constexpr int NPB = 128;
    int f2 = threadIdx.x % F2;
    int grp = threadIdx.x / F2;
    int f = 2 * f2;
    const float invN = 1.f / (float)N_NODES;
    float sm0 = 0.f, sm1 = 0.f, sq0 = 0.f, sq1 = 0.f;
#pragma unroll
    for (int s = 0; s < NSLICE; ++s) {
        sm0 += bnP[s * 2 * F + f];     sm1 += bnP[s * 2 * F + f + 1];
        sq0 += bnP[s * 2 * F + F + f]; sq1 += bnP[s * 2 * F + F + f + 1];
    }
    float m0 = sm0 * invN, m1 = sm1 * invN;
    float v0 = sq0 * invN - m0 * m0;
    float v1 = sq1 * invN - m1 * m1;
    float sc0 = rsqrtf(v0 + 1e-5f) * g[f];
    float sc1 = rsqrtf(v1 + 1e-5f) * g[f + 1];
    float bb0 = be[f] - m0 * sc0;
    float bb1 = be[f + 1] - m1 * sc1;
    int n0 = blockIdx.x * NPB;
    int nend = n0 + NPB; if (nend > N_NODES) nend = N_NODES;
    int n = n0 + grp;
    if (n >= nend) return;
    float p0 = 0.f, p1 = 0.f;
    int cg = batch[n];
    for (; n < nend; n += NGRP) {
        float2 xv = __half22float2(*reinterpret_cast<const __half2*>(x + (size_t)n * F + f));
        float y0 = xv.x * sc0 + bb0; y0 = y0 > 0.f ? y0 : 0.01f * y0;
        float y1 = xv.y * sc1 + bb1; y1 = y1 > 0.f ? y1 : 0.01f * y1;
        int bg = batch[n];
        if (bg != cg) {
            atomicAdd(&p[cg * POOL_F + poff + f], p0);
            atomicAdd(&p[cg * POOL_F + poff + f + 1], p1);
            p0 = p1 = 0.f; cg = bg;
        }
        p0 += y0; p1 += y1;
    }
    atomicAdd(&p[cg * POOL_F + poff + f], p0);
    atomicAdd(&p[cg * POOL_F + poff + f + 1], p1);
}

// ---------------- final MLP ----------------

__global__ void k_mlp(const float* __restrict__ p, const float* __restrict__ Wc1,
                      const float* __restrict__ bc1, const float* __restrict__ Wc2,
                      const float* __restrict__ bc2, const float* __restrict__ Wc3,
                      const float* __restrict__ bc3, float* __restrict__ out) {
    __shared__ float pr[POOL_F];
    __shared__ float h1[128];
    __shared__ float h2[64];
    int g = blockIdx.x, tid = threadIdx.x;
    for (int i = tid; i < POOL_F; i += 128) pr[i] = p[g * POOL_F + i];
    __syncthreads();
    float a = bc1[tid];
    for (int k = 0; k < POOL_F; ++k) a += pr[k] * Wc1[k * 128 + tid];
    a = a > 0.f ? a : 0.01f * a;
    h1[tid] = a;
    __syncthreads();
    if (tid < 64) {
        float b = bc2[tid];
        for (int k = 0; k < 128; ++k) b += h1[k] * Wc2[k * 64 + tid];
        b = b > 0.f ? b : 0.01f * b;
        h2[tid] = b;
    }
    __syncthreads();
    if (tid < 2) {
        float c = bc3[tid];
        for (int k = 0; k < 64; ++k) c += h2[k] * Wc3[k * 2 + tid];
        out[g * 2 + tid] = c;
    }
}

// ---------------- launch ----------------

extern "C" void kernel_launch(void* const* d_in, const int* in_sizes, int n_in,
                              void* d_out, int out_size, void* d_ws, size_t ws_size,
                              hipStream_t stream) {
    const float* x    = (const float*)d_in[0];
    const int*   ei   = (const int*)d_in[1];
    const int*   batch= (const int*)d_in[3];
    const float* W1  = (const float*)d_in[4];
    const float* as1 = (const float*)d_in[5];
    const float* ad1 = (const float*)d_in[6];
    const float* b1  = (const float*)d_in[7];
    const float* g1  = (const float*)d_in[8];
    const float* be1 = (const float*)d_in[9];
    const float* W2  = (const float*)d_in[10];
    const float* as2 = (const float*)d_in[11];
    const float* ad2 = (const float*)d_in[12];
    const float* b2  = (const float*)d_in[13];
    const float* g2  = (const float*)d_in[14];
    const float* be2 = (const float*)d_in[15];
    const float* W3  = (const float*)d_in[16];
    const float* as3 = (const float*)d_in[17];
    const float* ad3 = (const float*)d_in[18];
    const float* b3  = (const float*)d_in[19];
    const float* g3  = (const float*)d_in[20];
    const float* be3 = (const float*)d_in[21];
    const float* Wc1 = (const float*)d_in[22];
    const float* bc1 = (const float*)d_in[23];
    const float* Wc2 = (const float*)d_in[24];
    const float* bc2 = (const float*)d_in[25];
    const float* Wc3 = (const float*)d_in[26];
    const float* bc3 = (const float*)d_in[27];
    float* out = (float*)d_out;

    char* wsb = (char*)d_ws;
    size_t off = 0;
    auto alloc = [&](size_t b) -> void* {
        void* pp = wsb + off;
        off += (b + 255) & ~(size_t)255;
        return pp;
    };
    int*    adj      = (int*)alloc((size_t)E_TOT * 4);
    int*    rowstart = (int*)alloc((size_t)(N_NODES + 1) * 4);
    int*    deg      = (int*)alloc((size_t)N_NODES * 4);
    int*    cursor   = (int*)alloc((size_t)N_NODES * 4);
    int*    bsum     = (int*)alloc(256 * 4);
    float*  al_s     = (float*)alloc((size_t)N_NODES * 2 * 4);
    float*  al_d     = (float*)alloc((size_t)N_NODES * 2 * 4);
    float*  bn1      = (float*)alloc(NSLICE * 512 * 4);
    float*  bn2      = (float*)alloc(NSLICE * 512 * 4);
    float*  bn3      = (float*)alloc(NSLICE * 512 * 4);
    float*  p        = (float*)alloc((size_t)NGRAPH * POOL_F * 4);
    __half* WT1      = (__half*)alloc((size_t)64 * 128 * 2);
    __half* WT2      = (__half*)alloc((size_t)128 * 64 * 2);
    __half* WT3      = (__half*)alloc((size_t)256 * 128 * 2);
    __half* hbuf     = (__half*)alloc((size_t)N_NODES * 128 * 2);   // fp16 payload (layers 1,2)
    unsigned char* h8buf = (unsigned char*)alloc((size_t)N_NODES * 256); // fp8 payload (layer 3)
    __half* xbuf     = (__half*)alloc((size_t)N_NODES * 256 * 2);

    k_init<<<472, 256, 0, stream>>>(deg, cursor, p, bn1, W1, W2, W3, WT1, WT2, WT3);

    int eb4 = (E_TOT / 4 + 255) / 256;   // 4 edges per thread
    k_deg<<<eb4, 256, 0, stream>>>(ei + E_RAW_N, deg);
    k_scan1<<<SCAN_B, 256, 0, stream>>>(deg, bsum);
    k_scan3<<<SCAN_B, 256, 0, stream>>>(deg, bsum, rowstart);
    k_fill<<<eb4, 256, 0, stream>>>(ei, rowstart, cursor, adj);

    int wb = (N_NODES + 3) / 4;
    int bb = (N_NODES + 127) / 128;
    const int sb = 480;
    const int mb = 391;                  // ceil(ceil(50000/32)/4)

    // ---- layer 1: K=128, F=64 (fp16 payload) ----
    k_mfma<128, 64, false, float, __half><<<mb, 256, 0, stream>>>(
        x, WT1, nullptr, nullptr, nullptr, as1, ad1, hbuf, al_s, al_d);
    k_gather<64, 32, false><<<wb, 256, 0, stream>>>(rowstart, adj, hbuf, al_s, al_d, b1, xbuf);
    k_bnstats<64><<<sb, 256, 0, stream>>>(xbuf, bn1);
    k_bnpool<64><<<bb, 256, 0, stream>>>(xbuf, bn1, g1, be1, batch, p, 0);

    // ---- layer 2: K=64, F=128 (fp16 payload) ----
    k_mfma<64, 128, true, __half, __half><<<mb, 256, 0, stream>>>(
        xbuf, WT2, bn1, g1, be1, as2, ad2, hbuf, al_s, al_d);
    k_gather<128, 64, false><<<wb, 256, 0, stream>>>(rowstart, adj, hbuf, al_s, al_d, b2, xbuf);
    k_bnstats<128><<<sb, 256, 0, stream>>>(xbuf, bn2);
    k_bnpool<128><<<bb, 256, 0, stream>>>(xbuf, bn2, g2, be2, batch, p, 64);

    // ---- layer 3: K=128, F=256 (fp8 payload, 8B/lane) ----
    k_mfma<128, 256, true, __half, unsigned char><<<mb, 256, 0, stream>>>(
        xbuf, WT3, bn2, g2, be2, as3, ad3, h8buf, al_s, al_d);
    k_gather<256, 128, true><<<wb, 256, 0, stream>>>(rowstart, adj, h8buf, al_s, al_d, b3, xbuf);
    k_bnstats<256><<<sb, 256, 0, stream>>>(xbuf, bn3);
    k_bnpool<256><<<bb, 256, 0, stream>>>(xbuf, bn3, g3, be3, batch, p, 192);

    // ---- readout MLP ----
    k_mlp<<<NGRAPH, 128, 0, stream>>>(p, Wc1, bc1, Wc2, bc2, Wc3, bc3, out);
}

// Round 13
// 291.151 us; speedup vs baseline: 1.1728x; 1.1728x over previous
//
#include <hip/hip_runtime.h>
#include <hip/hip_fp16.h>
#include <math.h>

#define N_NODES 50000
#define E_RAW_N 800000
#define E_TOT   (E_RAW_N + N_NODES)   // 850000 (self-loops appended)
#define NGRAPH  256
#define POOL_F  448                    // 64 + 128 + 256
#define SCAN_B  196                    // ceil(N_NODES / 256)
#define NSLICE  4                      // bnstats partial slices
#define MBLK    391                    // mfma blocks: ceil(ceil(50000/32)/4)
#define EBLK    3321                   // edge blocks: ceil(850000/256)
#define PBLK    391                    // bnpool blocks: ceil(50000/128)

using f16x8 = __attribute__((ext_vector_type(8))) _Float16;
using f32x4 = __attribute__((ext_vector_type(4))) float;

// ---------------- W transpose helper (fp16 WT[F][K]) ----------------

template<int K, int F>
__device__ void do_wt(const float* __restrict__ W, __half* __restrict__ WT, int blk) {
    int i = blk * 256 + threadIdx.x;
    if (i >= F * (K / 8)) return;
    int f = i / (K / 8);
    int kb = (i % (K / 8)) * 8;
    __half tmp[8];
#pragma unroll
    for (int j = 0; j < 8; ++j) tmp[j] = __float2half(W[(size_t)(kb + j) * F + f]);
    *reinterpret_cast<uint4*>(WT + (size_t)f * K + kb) = *reinterpret_cast<uint4*>(tmp);
}

// ---------------- init + weight transpose (one dispatch) ----------------

__global__ void k_init(int* __restrict__ deg, float* __restrict__ p,
                       float* __restrict__ bn,
                       const float* __restrict__ W1, const float* __restrict__ W2,
                       const float* __restrict__ W3, __half* __restrict__ WT1,
                       __half* __restrict__ WT2, __half* __restrict__ WT3) {
    int b = blockIdx.x;
    if (b < 448) {
        int i = b * 256 + threadIdx.x;
        if (i < N_NODES) deg[i] = 0;
        if (i < NGRAPH * POOL_F) p[i] = 0.f;
        if (i < NSLICE * 512 * 3) bn[i] = 0.f;
    } else {
        int wb = b - 448;
        if (wb < 4)       do_wt<128, 64>(W1, WT1, wb);
        else if (wb < 8)  do_wt<64, 128>(W2, WT2, wb - 4);
        else              do_wt<128, 256>(W3, WT3, wb - 8);
    }
}

// ---------------- CSR build pieces ----------------

__device__ inline void degrank_body(int bid, const int* __restrict__ dst_raw,
                                    int* __restrict__ deg, int* __restrict__ rank) {
    int e = bid * 256 + threadIdx.x;
    if (e >= E_TOT) return;
    int d = (e < E_RAW_N) ? dst_raw[e] : (e - E_RAW_N);
    rank[e] = atomicAdd(&deg[d], 1);
}

__global__ void k_scan1(const int* __restrict__ deg, int* __restrict__ bsum) {
    __shared__ int red[256];
    int i = blockIdx.x * 256 + threadIdx.x;
    int v = (i < N_NODES) ? deg[i] : 0;
    red[threadIdx.x] = v;
    __syncthreads();
    for (int o = 128; o > 0; o >>= 1) {
        if (threadIdx.x < o) red[threadIdx.x] += red[threadIdx.x + o];
        __syncthreads();
    }
    if (threadIdx.x == 0) bsum[blockIdx.x] = red[0];
}

__global__ void k_scan3(const int* __restrict__ deg, const int* __restrict__ bsum,
                        int* __restrict__ rowstart) {
    __shared__ int pre[256];
    __shared__ int s[256];
    int tid = threadIdx.x;
    pre[tid] = (tid < (int)blockIdx.x) ? bsum[tid] : 0;
    int i = blockIdx.x * 256 + tid;
    int v = (i < N_NODES) ? deg[i] : 0;
    s[tid] = v;
    __syncthreads();
    for (int o = 128; o > 0; o >>= 1) {
        if (tid < o) pre[tid] += pre[tid + o];
        __syncthreads();
    }
    for (int o = 1; o < 256; o <<= 1) {
        int t = (tid >= o) ? s[tid - o] : 0;
        __syncthreads();
        s[tid] += t;
        __syncthreads();
    }
    if (i < N_NODES) rowstart[i] = pre[0] + s[tid] - v;
    if (i == 0) rowstart[N_NODES] = E_TOT;
}

// atomic-free fill: position = rowstart[d] + precomputed rank
__global__ void k_fill(const int* __restrict__ ei, const int* __restrict__ rowstart,
                       const int* __restrict__ rank, int* __restrict__ adj) {
    int e = blockIdx.x * blockDim.x + threadIdx.x;
    if (e >= E_TOT) return;
    int s, d;
    if (e < E_RAW_N) { s = ei[e]; d = ei[E_RAW_N + e]; }
    else             { s = d = e - E_RAW_N; }
    adj[rowstart[d] + rank[e]] = s;
}

// ---------------- bnpool body (shared by standalone + fused) ----------------

template<int F>
__device__ void bnpool_body(int bid, const __half* __restrict__ x,
                            const float* __restrict__ bnP, const float* __restrict__ g,
                            const float* __restrict__ be, const int* __restrict__ batch,
                            float* __restrict__ p, int poff) {
    constexpr int F2 = F / 2;
    constexpr int NGRP = 512 / F;
    constexpr int NPB = 128;
    int f2 = threadIdx.x % F2;
    int grp = threadIdx.x / F2;
    int f = 2 * f2;
    const float invN = 1.f / (float)N_NODES;
    float sm0 = 0.f, sm1 = 0.f, sq0 = 0.f, sq1 = 0.f;
#pragma unroll
    for (int s = 0; s < NSLICE; ++s) {
        sm0 += bnP[s * 2 * F + f];     sm1 += bnP[s * 2 * F + f + 1];
        sq0 += bnP[s * 2 * F + F + f]; sq1 += bnP[s * 2 * F + F + f + 1];
    }
    float m0 = sm0 * invN, m1 = sm1 * invN;
    float v0 = sq0 * invN - m0 * m0;
    float v1 = sq1 * invN - m1 * m1;
    float sc0 = rsqrtf(v0 + 1e-5f) * g[f];
    float sc1 = rsqrtf(v1 + 1e-5f) * g[f + 1];
    float bb0 = be[f] - m0 * sc0;
    float bb1 = be[f + 1] - m1 * sc1;
    int n0 = bid * NPB;
    int nend = n0 + NPB; if (nend > N_NODES) nend = N_NODES;
    int n = n0 + grp;
    if (n >= nend) return;
    float p0 = 0.f, p1 = 0.f;
    int cg = batch[n];
    for (; n < nend; n += NGRP) {
        float2 xv = __half22float2(*reinterpret_cast<const __half2*>(x + (size_t)n * F + f));
        float y0 = xv.x * sc0 + bb0; y0 = y0 > 0.f ? y0 : 0.01f * y0;
        float y1 = xv.y * sc1 + bb1; y1 = y1 > 0.f ? y1 : 0.01f * y1;
        int bg = batch[n];
        if (bg != cg) {
            atomicAdd(&p[cg * POOL_F + poff + f], p0);
            atomicAdd(&p[cg * POOL_F + poff + f + 1], p1);
            p0 = p1 = 0.f; cg = bg;
        }
        p0 += y0; p1 += y1;
    }
    atomicAdd(&p[cg * POOL_F + poff + f], p0);
    atomicAdd(&p[cg * POOL_F + poff + f + 1], p1);
}

template<int F>
__global__ void k_bnpool(const __half* __restrict__ x, const float* __restrict__ bnP,
                         const float* __restrict__ g, const float* __restrict__ be,
                         const int* __restrict__ batch, float* __restrict__ p, int poff) {
    bnpool_body<F>(blockIdx.x, x, bnP, g, be, batch, p, poff);
}

// ---------------- MFMA GEMM + fused side work ----------------
// SIDE: 0 = none, 1 = degrank (blocks >= MBLK), 2 = bnpool<K> of previous layer.

template<int K, int F, bool BNIN, typename TIN, typename TOUT, int SIDE>
__global__ void __launch_bounds__(256) k_mfma(
        const TIN* __restrict__ x, const __half* __restrict__ WT,
        const float* __restrict__ bnP,
        const float* __restrict__ g, const float* __restrict__ be,
        const float* __restrict__ a_src, const float* __restrict__ a_dst,
        void* __restrict__ hout, float* __restrict__ al_s, float* __restrict__ al_d,
        const int* __restrict__ dst_raw, int* __restrict__ deg, int* __restrict__ rank,
        const int* __restrict__ batch, float* __restrict__ pp, int poff) {
    if constexpr (SIDE == 1) {
        if (blockIdx.x >= MBLK) { degrank_body(blockIdx.x - MBLK, dst_raw, deg, rank); return; }
    } else if constexpr (SIDE == 2) {
        if (blockIdx.x >= MBLK) {
            bnpool_body<K>(blockIdx.x - MBLK, (const __half*)x, bnP, g, be, batch, pp, poff);
            return;
        }
    }
    constexpr int NF = F / 16;
    constexpr int KS = K / 32;
    constexpr int MT = 2;
    __shared__ float scs[K], bbs[K];
    int tid = threadIdx.x;
    if constexpr (BNIN) {
        const float invN = 1.f / (float)N_NODES;
        for (int i = tid; i < K; i += 256) {
            float sm = 0.f, sq = 0.f;
#pragma unroll
            for (int s = 0; s < NSLICE; ++s) {
                sm += bnP[s * 2 * K + i];
                sq += bnP[s * 2 * K + K + i];
            }
            float mean = sm * invN;
            float var  = sq * invN - mean * mean;
            float sc = rsqrtf(var + 1e-5f) * g[i];
            scs[i] = sc;
            bbs[i] = be[i] - mean * sc;
        }
        __syncthreads();
    }
    int wave = tid >> 6, lane = tid & 63;
    int col = lane & 15;
    int kg  = lane >> 4;
    long n_base = ((long)blockIdx.x * 4 + wave) * (MT * 16);
    if (n_base >= N_NODES) return;

    bool mv[MT];
#pragma unroll
    for (int m = 0; m < MT; ++m) mv[m] = (n_base + m * 16) < N_NODES;

    f32x4 acc[MT][NF];
#pragma unroll
    for (int m = 0; m < MT; ++m)
#pragma unroll
        for (int t = 0; t < NF; ++t) acc[m][t] = (f32x4){0.f, 0.f, 0.f, 0.f};

    for (int ks = 0; ks < KS; ++ks) {
        int kb = ks * 32 + kg * 8;
        f16x8 af[MT];
#pragma unroll
        for (int m = 0; m < MT; ++m) {
            if (!mv[m]) { af[m] = (f16x8){}; continue; }
            long nrow = n_base + m * 16 + col;
            if constexpr (sizeof(TIN) == 2) {
                uint4 u = *reinterpret_cast<const uint4*>((const __half*)x + nrow * K + kb);
                if constexpr (BNIN) {
                    const __half* hp = reinterpret_cast<const __half*>(&u);
                    f16x8 a;
#pragma unroll
                    for (int j = 0; j < 8; ++j) {
                        float y = __half2float(hp[j]) * scs[kb + j] + bbs[kb + j];
                        y = y > 0.f ? y : 0.01f * y;
                        a[j] = (_Float16)y;
                    }
                    af[m] = a;
                } else {
                    af[m] = *reinterpret_cast<const f16x8*>(&u);
                }
            } else {
                const float* xp = (const float*)x + nrow * K + kb;
                float4 v0 = *reinterpret_cast<const float4*>(xp);
                float4 v1 = *reinterpret_cast<const float4*>(xp + 4);
                f16x8 a;
                a[0] = (_Float16)v0.x; a[1] = (_Float16)v0.y;
                a[2] = (_Float16)v0.z; a[3] = (_Float16)v0.w;
                a[4] = (_Float16)v1.x; a[5] = (_Float16)v1.y;
                a[6] = (_Float16)v1.z; a[7] = (_Float16)v1.w;
                af[m] = a;
            }
        }
#pragma unroll
        for (int t = 0; t < NF; ++t) {
            f16x8 bf = *reinterpret_cast<const f16x8*>(WT + (size_t)(t * 16 + col) * K + kb);
            acc[0][t] = __builtin_amdgcn_mfma_f32_16x16x32_f16(af[0], bf, acc[0][t], 0, 0, 0);
            if constexpr (MT > 1)
                acc[1][t] = __builtin_amdgcn_mfma_f32_16x16x32_f16(af[1], bf, acc[1][t], 0, 0, 0);
        }
    }

#pragma unroll
    for (int m = 0; m < MT; ++m) {
        if (!mv[m]) continue;
#pragma unroll
        for (int t = 0; t < NF; ++t) {
#pragma unroll
            for (int r = 0; r < 4; ++r) {
                long n = n_base + m * 16 + kg * 4 + r;
                float v = acc[m][t][r];
                if constexpr (sizeof(TOUT) == 1) {
                    int pk = __builtin_amdgcn_cvt_pk_fp8_f32(v, v, 0, false);
                    reinterpret_cast<unsigned char*>(hout)[n * F + t * 16 + col] =
                        (unsigned char)(pk & 0xff);
                } else {
                    reinterpret_cast<__half*>(hout)[n * F + t * 16 + col] = __float2half(v);
                }
            }
        }
#pragma unroll
        for (int r = 0; r < 4; ++r) {
            float ss0 = 0.f, sd0 = 0.f, ss1 = 0.f, sd1 = 0.f;
#pragma unroll
            for (int t = 0; t < NF; ++t) {
                float v = acc[m][t][r];
                float as = a_src[t * 16 + col];
                float ad = a_dst[t * 16 + col];
                if (t < NF / 2) { ss0 += v * as; sd0 += v * ad; }
                else            { ss1 += v * as; sd1 += v * ad; }
            }
#pragma unroll
            for (int o = 1; o < 16; o <<= 1) {
                ss0 += __shfl_xor(ss0, o); sd0 += __shfl_xor(sd0, o);
                ss1 += __shfl_xor(ss1, o); sd1 += __shfl_xor(sd1, o);
            }
            if (col == 0) {
                long n = n_base + m * 16 + kg * 4 + r;
                al_s[n * 2]     = ss0; al_s[n * 2 + 1] = ss1;
                al_d[n * 2]     = sd0; al_d[n * 2 + 1] = sd1;
            }
        }
    }
}

// ---------------- per-dst gather: masked wide steps + adj prefetch ----------

template<bool FP8> struct PayT;
template<> struct PayT<false> { using T = uint4; };
template<> struct PayT<true>  { using T = uint2; };

template<bool FP8>
__device__ inline void accum8(typename PayT<FP8>::T u, float ee, float acc[8]) {
    if constexpr (FP8) {
        auto f0 = __builtin_amdgcn_cvt_pk_f32_fp8(u.x, false);
        auto f1 = __builtin_amdgcn_cvt_pk_f32_fp8(u.x, true);
        auto f2 = __builtin_amdgcn_cvt_pk_f32_fp8(u.y, false);
        auto f3 = __builtin_amdgcn_cvt_pk_f32_fp8(u.y, true);
        acc[0] += ee * f0[0]; acc[1] += ee * f0[1];
        acc[2] += ee * f1[0]; acc[3] += ee * f1[1];
        acc[4] += ee * f2[0]; acc[5] += ee * f2[1];
        acc[6] += ee * f3[0]; acc[7] += ee * f3[1];
    } else {
        float2 f0 = __half22float2(*reinterpret_cast<const __half2*>(&u.x));
        float2 f1 = __half22float2(*reinterpret_cast<const __half2*>(&u.y));
        float2 f2 = __half22float2(*reinterpret_cast<const __half2*>(&u.z));
        float2 f3 = __half22float2(*reinterpret_cast<const __half2*>(&u.w));
        acc[0] += ee * f0.x; acc[1] += ee * f0.y;
        acc[2] += ee * f1.x; acc[3] += ee * f1.y;
        acc[4] += ee * f2.x; acc[5] += ee * f2.y;
        acc[6] += ee * f3.x; acc[7] += ee * f3.y;
    }
}

template<int F, int C, bool FP8>
__global__ void __launch_bounds__(256) k_gather(
        const int* __restrict__ rowstart, const int* __restrict__ adj,
        const void* __restrict__ hv, const float* __restrict__ al_s,
        const float* __restrict__ al_d, const float* __restrict__ bias,
        __half* __restrict__ xpre) {
    using LT = typename PayT<FP8>::T;
    constexpr int HPL = 8;
    constexpr int LPE = F / HPL;
    constexpr int EPI = 64 / LPE;
    constexpr int UNR = (EPI >= 8) ? 4 : (16 / EPI);
    constexpr int STEP = UNR * EPI;
    constexpr unsigned RSH = FP8 ? 8 : ((F == 64) ? 7 : 8);
    int wave = (blockIdx.x * 256 + threadIdx.x) >> 6;
    int lane = threadIdx.x & 63;
    if (wave >= N_NODES) return;
    int n = wave;
    int rs = rowstart[n], re = rowstart[n + 1];
    float2 aldv = *reinterpret_cast<const float2*>(al_d + n * 2);

    const int es = lane / LPE;
    const int fl = lane % LPE;
    const unsigned fi = fl * HPL;
    const int hd = (fi >= C) ? 1 : 0;
    const float alh = hd ? aldv.y : aldv.x;
    const char* base = (const char*)hv;
    const char* alsb = (const char*)al_s;
    const unsigned fioff = FP8 ? fi : fi * 2;

    float acc[HPL];
#pragma unroll
    for (int j = 0; j < HPL; ++j) acc[j] = 0.f;
    float seh = 0.f;

    int nsteps = (re - rs + STEP - 1) / STEP;
    unsigned sN[UNR];
#pragma unroll
    for (int u = 0; u < UNR; ++u) {
        int e = rs + u * EPI + es;
        sN[u] = (unsigned)adj[min(e, re - 1)];
    }
    for (int t = 0; t < nsteps; ++t) {
        int ibase = rs + t * STEP;
        unsigned sC[UNR];
#pragma unroll
        for (int u = 0; u < UNR; ++u) sC[u] = sN[u];
        if (t + 1 < nsteps) {
            int nb = ibase + STEP;
#pragma unroll
            for (int u = 0; u < UNR; ++u) {
                int e = nb + u * EPI + es;
                sN[u] = (unsigned)adj[min(e, re - 1)];
            }
        }
        float alsN[UNR];
        LT hvN[UNR];
#pragma unroll
        for (int u = 0; u < UNR; ++u) {
            alsN[u] = *reinterpret_cast<const float*>(alsb + ((sC[u] << 3) | (unsigned)(hd << 2)));
            hvN[u] = *reinterpret_cast<const LT*>(base + ((sC[u] << RSH) + fioff));
        }
#pragma unroll
        for (int u = 0; u < UNR; ++u) {
            bool valid = (ibase + u * EPI + es) < re;
            float v = alsN[u] + alh; v = v > 0.f ? v : 0.2f * v;
            v = fminf(v, 80.f);
            float ee = valid ? __expf(v) : 0.f;
            seh += ee;
            accum8<FP8>(hvN[u], ee, acc);
        }
    }

#pragma unroll
    for (int o = LPE; o < 64; o <<= 1) {
        seh += __shfl_xor(seh, o);
#pragma unroll
        for (int j = 0; j < HPL; ++j) acc[j] += __shfl_xor(acc[j], o);
    }

    if (es == 0) {
        float inv = 1.f / (seh + 1e-16f);
        const float* bp = bias + fi;
        __half2 o0 = __floats2half2_rn(acc[0] * inv + bp[0], acc[1] * inv + bp[1]);
        __half2 o1 = __floats2half2_rn(acc[2] * inv + bp[2], acc[3] * inv + bp[3]);
        __half2 o2 = __floats2half2_rn(acc[4] * inv + bp[4], acc[5] * inv + bp[5]);
        __half2 o3 = __floats2half2_rn(acc[6] * inv + bp[6], acc[7] * inv + bp[7]);
        uint4 u;
        u.x = *reinterpret_cast<unsigned int*>(&o0);
        u.y = *reinterpret_cast<unsigned int*>(&o1);
        u.z = *reinterpret_cast<unsigned int*>(&o2);
        u.w = *reinterpret_cast<unsigned int*>(&o3);
        *reinterpret_cast<uint4*>(xpre + (size_t)n * F + fi) = u;
    }
}

// ---------------- BatchNorm stats: 4-slice partials, 480 blocks ------------

template<int F>
__global__ void __launch_bounds__(256) k_bnstats(const __half* __restrict__ x,
        float* __restrict__ bnP) {
    constexpr int SLOTS = F / 8;
    constexpr int RPI   = 256 / SLOTS;
    __shared__ float ls[256][8];
    int tid = threadIdx.x;
    int slot = tid % SLOTS;
    int r0 = tid / SLOTS;
    int slice = blockIdx.x & (NSLICE - 1);
    float s[8], q[8];
#pragma unroll
    for (int j = 0; j < 8; ++j) { s[j] = 0.f; q[j] = 0.f; }
    int stride = gridDim.x * RPI;
    for (int n = blockIdx.x * RPI + r0; n < N_NODES; n += stride) {
        uint4 u = *reinterpret_cast<const uint4*>(x + (size_t)n * F + slot * 8);
        float2 f0 = __half22float2(*reinterpret_cast<__half2*>(&u.x));
        float2 f1 = __half22float2(*reinterpret_cast<__half2*>(&u.y));
        float2 f2 = __half22float2(*reinterpret_cast<__half2*>(&u.z));
        float2 f3 = __half22float2(*reinterpret_cast<__half2*>(&u.w));
        float v[8] = {f0.x, f0.y, f1.x, f1.y, f2.x, f2.y, f3.x, f3.y};
#pragma unroll
        for (int j = 0; j < 8; ++j) { s[j] += v[j]; q[j] += v[j] * v[j]; }
    }
#pragma unroll
    for (int j = 0; j < 8; ++j) ls[tid][j] = s[j];
    __syncthreads();
    if (tid < F) {
        int sl = tid / 8, j = tid % 8;
        float t = 0.f;
        for (int r = 0; r < RPI; ++r) t += ls[r * SLOTS + sl][j];
        atomicAdd(&bnP[slice * 2 * F + tid], t);
    }
    __syncthreads();
#pragma unroll
    for (int j = 0; j < 8; ++j) ls[tid][j] = q[j];
    __syncthreads();
    if (tid < F) {
        int sl = tid / 8, j = tid % 8;
        float t = 0.f;
        for (int r = 0; r < RPI; ++r) t += ls[r * SLOTS + sl][j];
        atomicAdd(&bnP[slice * 2 * F + F + tid], t);
    }
}

// ---------------- final MLP ----------------

__global__ void k_mlp(const float* __restrict__ p, const float* __restrict__ Wc1,
                      const float* __restrict__ bc1, const float* __restrict__ Wc2,
                      const float* __restrict__ bc2, const float* __restrict__ Wc3,
                      const float* __restrict__ bc3, float* __restrict__ out) {
    __shared__ float pr[POOL_F];
    __shared__ float h1[128];
    __shared__ float h2[64];
    int g = blockIdx.x, tid = threadIdx.x;
    for (int i = tid; i < POOL_F; i += 128) pr[i] = p[g * POOL_F + i];
    __syncthreads();
    float a = bc1[tid];
    for (int k = 0; k < POOL_F; ++k) a += pr[k] * Wc1[k * 128 + tid];
    a = a > 0.f ? a : 0.01f * a;
    h1[tid] = a;
    __syncthreads();
    if (tid < 64) {
        float b = bc2[tid];
        for (int k = 0; k < 128; ++k) b += h1[k] * Wc2[k * 64 + tid];
        b = b > 0.f ? b : 0.01f * b;
        h2[tid] = b;
    }
    __syncthreads();
    if (tid < 2) {
        float c = bc3[tid];
        for (int k = 0; k < 64; ++k) c += h2[k] * Wc3[k * 2 + tid];
        out[g * 2 + tid] = c;
    }
}

// ---------------- launch ----------------

extern "C" void kernel_launch(void* const* d_in, const int* in_sizes, int n_in,
                              void* d_out, int out_size, void* d_ws, size_t ws_size,
                              hipStream_t stream) {
    const float* x    = (const float*)d_in[0];
    const int*   ei   = (const int*)d_in[1];
    const int*   batch= (const int*)d_in[3];
    const float* W1  = (const float*)d_in[4];
    const float* as1 = (const float*)d_in[5];
    const float* ad1 = (const float*)d_in[6];
    const float* b1  = (const float*)d_in[7];
    const float* g1  = (const float*)d_in[8];
    const float* be1 = (const float*)d_in[9];
    const float* W2  = (const float*)d_in[10];
    const float* as2 = (const float*)d_in[11];
    const float* ad2 = (const float*)d_in[12];
    const float* b2  = (const float*)d_in[13];
    const float* g2  = (const float*)d_in[14];
    const float* be2 = (const float*)d_in[15];
    const float* W3  = (const float*)d_in[16];
    const float* as3 = (const float*)d_in[17];
    const float* ad3 = (const float*)d_in[18];
    const float* b3  = (const float*)d_in[19];
    const float* g3  = (const float*)d_in[20];
    const float* be3 = (const float*)d_in[21];
    const float* Wc1 = (const float*)d_in[22];
    const float* bc1 = (const float*)d_in[23];
    const float* Wc2 = (const float*)d_in[24];
    const float* bc2 = (const float*)d_in[25];
    const float* Wc3 = (const float*)d_in[26];
    const float* bc3 = (const float*)d_in[27];
    float* out = (float*)d_out;

    char* wsb = (char*)d_ws;
    size_t off = 0;
    auto alloc = [&](size_t b) -> void* {
        void* pp = wsb + off;
        off += (b + 255) & ~(size_t)255;
        return pp;
    };
    int*    adj      = (int*)alloc((size_t)E_TOT * 4);
    int*    rank     = (int*)alloc((size_t)E_TOT * 4);
    int*    rowstart = (int*)alloc((size_t)(N_NODES + 1) * 4);
    int*    deg      = (int*)alloc((size_t)N_NODES * 4);
    int*    bsum     = (int*)alloc(256 * 4);
    float*  al_s     = (float*)alloc((size_t)N_NODES * 2 * 4);
    float*  al_d     = (float*)alloc((size_t)N_NODES * 2 * 4);
    float*  bn1      = (float*)alloc(NSLICE * 512 * 4);
    float*  bn2      = (float*)alloc(NSLICE * 512 * 4);
    float*  bn3      = (float*)alloc(NSLICE * 512 * 4);
    float*  p        = (float*)alloc((size_t)NGRAPH * POOL_F * 4);
    __half* WT1      = (__half*)alloc((size_t)64 * 128 * 2);
    __half* WT2      = (__half*)alloc((size_t)128 * 64 * 2);
    __half* WT3      = (__half*)alloc((size_t)256 * 128 * 2);
    __half* hbuf     = (__half*)alloc((size_t)N_NODES * 128 * 2);   // fp16 payload (layers 1,2)
    unsigned char* h8buf = (unsigned char*)alloc((size_t)N_NODES * 256); // fp8 payload (layer 3)
    __half* xbuf     = (__half*)alloc((size_t)N_NODES * 256 * 2);

    k_init<<<472, 256, 0, stream>>>(deg, p, bn1, W1, W2, W3, WT1, WT2, WT3);

    int wb = (N_NODES + 3) / 4;
    const int sb = 480;

    // ---- layer-1 GEMM fused with degrank (independent work) ----
    k_mfma<128, 64, false, float, __half, 1><<<MBLK + EBLK, 256, 0, stream>>>(
        x, WT1, nullptr, nullptr, nullptr, as1, ad1, hbuf, al_s, al_d,
        ei + E_RAW_N, deg, rank, nullptr, nullptr, 0);
    k_scan1<<<SCAN_B, 256, 0, stream>>>(deg, bsum);
    k_scan3<<<SCAN_B, 256, 0, stream>>>(deg, bsum, rowstart);
    k_fill<<<EBLK, 256, 0, stream>>>(ei, rowstart, rank, adj);

    // ---- layer 1 gather/stats ----
    k_gather<64, 32, false><<<wb, 256, 0, stream>>>(rowstart, adj, hbuf, al_s, al_d, b1, xbuf);
    k_bnstats<64><<<sb, 256, 0, stream>>>(xbuf, bn1);

    // ---- layer 2 GEMM fused with bnpool1 ----
    k_mfma<64, 128, true, __half, __half, 2><<<MBLK + PBLK, 256, 0, stream>>>(
        xbuf, WT2, bn1, g1, be1, as2, ad2, hbuf, al_s, al_d,
        nullptr, nullptr, nullptr, batch, p, 0);
    k_gather<128, 64, false><<<wb, 256, 0, stream>>>(rowstart, adj, hbuf, al_s, al_d, b2, xbuf);
    k_bnstats<128><<<sb, 256, 0, stream>>>(xbuf, bn2);

    // ---- layer 3 GEMM fused with bnpool2 ----
    k_mfma<128, 256, true, __half, unsigned char, 2><<<MBLK + PBLK, 256, 0, stream>>>(
        xbuf, WT3, bn2, g2, be2, as3, ad3, h8buf, al_s, al_d,
        nullptr, nullptr, nullptr, batch, p, 64);
    k_gather<256, 128, true><<<wb, 256, 0, stream>>>(rowstart, adj, h8buf, al_s, al_d, b3, xbuf);
    k_bnstats<256><<<sb, 256, 0, stream>>>(xbuf, bn3);

    // ---- bnpool3 + readout MLP ----
    k_bnpool<256><<<PBLK, 256, 0, stream>>>(xbuf, bn3, g3, be3, batch, p, 192);
    k_mlp<<<NGRAPH, 128, 0, stream>>>(p, Wc1, bc1, Wc2, bc2, Wc3, bc3, out);
}

// Round 14
// 276.819 us; speedup vs baseline: 1.2335x; 1.0518x over previous
//
#include <hip/hip_runtime.h>
#include <hip/hip_fp16.h>
#include <math.h>

#define N_NODES 50000
#define E_RAW_N 800000
#define E_TOT   (E_RAW_N + N_NODES)   // 850000 (self-loops appended)
#define NGRAPH  256
#define POOL_F  448                    // 64 + 128 + 256
#define SCAN_B  196                    // ceil(N_NODES / 256)
#define NSLICE  4                      // bnstats partial slices
#define MBLK    391                    // mfma blocks: ceil(ceil(50000/32)/4)
#define EBLK    3321                   // edge blocks: ceil(850000/256)
#define PBLK    391                    // bnpool blocks: ceil(50000/128)

using f16x8 = __attribute__((ext_vector_type(8))) _Float16;
using f32x4 = __attribute__((ext_vector_type(4))) float;

// ---------------- W transpose helper (fp16 WT[F][K]) ----------------

template<int K, int F>
__device__ void do_wt(const float* __restrict__ W, __half* __restrict__ WT, int blk) {
    int i = blk * 256 + threadIdx.x;
    if (i >= F * (K / 8)) return;
    int f = i / (K / 8);
    int kb = (i % (K / 8)) * 8;
    __half tmp[8];
#pragma unroll
    for (int j = 0; j < 8; ++j) tmp[j] = __float2half(W[(size_t)(kb + j) * F + f]);
    *reinterpret_cast<uint4*>(WT + (size_t)f * K + kb) = *reinterpret_cast<uint4*>(tmp);
}

// ---------------- init + weight transpose (one dispatch) ----------------

__global__ void k_init(int* __restrict__ deg, float* __restrict__ p,
                       float* __restrict__ bn,
                       const float* __restrict__ W1, const float* __restrict__ W2,
                       const float* __restrict__ W3, __half* __restrict__ WT1,
                       __half* __restrict__ WT2, __half* __restrict__ WT3) {
    int b = blockIdx.x;
    if (b < 448) {
        int i = b * 256 + threadIdx.x;
        if (i < N_NODES) deg[i] = 0;
        if (i < NGRAPH * POOL_F) p[i] = 0.f;
        if (i < NSLICE * 512 * 3) bn[i] = 0.f;
    } else {
        int wb = b - 448;
        if (wb < 4)       do_wt<128, 64>(W1, WT1, wb);
        else if (wb < 8)  do_wt<64, 128>(W2, WT2, wb - 4);
        else              do_wt<128, 256>(W3, WT3, wb - 8);
    }
}

// ---------------- CSR build pieces ----------------

__device__ inline void degrank_body(int bid, const int* __restrict__ dst_raw,
                                    int* __restrict__ deg, int* __restrict__ rank) {
    int e = bid * 256 + threadIdx.x;
    if (e >= E_TOT) return;
    int d = (e < E_RAW_N) ? dst_raw[e] : (e - E_RAW_N);
    rank[e] = atomicAdd(&deg[d], 1);
}

__global__ void k_scan1(const int* __restrict__ deg, int* __restrict__ bsum) {
    __shared__ int red[256];
    int i = blockIdx.x * 256 + threadIdx.x;
    int v = (i < N_NODES) ? deg[i] : 0;
    red[threadIdx.x] = v;
    __syncthreads();
    for (int o = 128; o > 0; o >>= 1) {
        if (threadIdx.x < o) red[threadIdx.x] += red[threadIdx.x + o];
        __syncthreads();
    }
    if (threadIdx.x == 0) bsum[blockIdx.x] = red[0];
}

__global__ void k_scan3(const int* __restrict__ deg, const int* __restrict__ bsum,
                        int* __restrict__ rowstart) {
    __shared__ int pre[256];
    __shared__ int s[256];
    int tid = threadIdx.x;
    pre[tid] = (tid < (int)blockIdx.x) ? bsum[tid] : 0;
    int i = blockIdx.x * 256 + tid;
    int v = (i < N_NODES) ? deg[i] : 0;
    s[tid] = v;
    __syncthreads();
    for (int o = 128; o > 0; o >>= 1) {
        if (tid < o) pre[tid] += pre[tid + o];
        __syncthreads();
    }
    for (int o = 1; o < 256; o <<= 1) {
        int t = (tid >= o) ? s[tid - o] : 0;
        __syncthreads();
        s[tid] += t;
        __syncthreads();
    }
    if (i < N_NODES) rowstart[i] = pre[0] + s[tid] - v;
    if (i == 0) rowstart[N_NODES] = E_TOT;
}

__global__ void k_fill(const int* __restrict__ ei, const int* __restrict__ rowstart,
                       const int* __restrict__ rank, int* __restrict__ adj) {
    int e = blockIdx.x * blockDim.x + threadIdx.x;
    if (e >= E_TOT) return;
    int s, d;
    if (e < E_RAW_N) { s = ei[e]; d = ei[E_RAW_N + e]; }
    else             { s = d = e - E_RAW_N; }
    adj[rowstart[d] + rank[e]] = s;
}

// ---------------- bnpool body (shared by standalone + fused) ----------------

template<int F>
__device__ void bnpool_body(int bid, const __half* __restrict__ x,
                            const float* __restrict__ bnP, const float* __restrict__ g,
                            const float* __restrict__ be, const int* __restrict__ batch,
                            float* __restrict__ p, int poff) {
    constexpr int F2 = F / 2;
    constexpr int NGRP = 512 / F;
    constexpr int NPB = 128;
    int f2 = threadIdx.x % F2;
    int grp = threadIdx.x / F2;
    int f = 2 * f2;
    const float invN = 1.f / (float)N_NODES;
    float sm0 = 0.f, sm1 = 0.f, sq0 = 0.f, sq1 = 0.f;
#pragma unroll
    for (int s = 0; s < NSLICE; ++s) {
        sm0 += bnP[s * 2 * F + f];     sm1 += bnP[s * 2 * F + f + 1];
        sq0 += bnP[s * 2 * F + F + f]; sq1 += bnP[s * 2 * F + F + f + 1];
    }
    float m0 = sm0 * invN, m1 = sm1 * invN;
    float v0 = sq0 * invN - m0 * m0;
    float v1 = sq1 * invN - m1 * m1;
    float sc0 = rsqrtf(v0 + 1e-5f) * g[f];
    float sc1 = rsqrtf(v1 + 1e-5f) * g[f + 1];
    float bb0 = be[f] - m0 * sc0;
    float bb1 = be[f + 1] - m1 * sc1;
    int n0 = bid * NPB;
    int nend = n0 + NPB; if (nend > N_NODES) nend = N_NODES;
    int n = n0 + grp;
    if (n >= nend) return;
    float p0 = 0.f, p1 = 0.f;
    int cg = batch[n];
    for (; n < nend; n += NGRP) {
        float2 xv = __half22float2(*reinterpret_cast<const __half2*>(x + (size_t)n * F + f));
        float y0 = xv.x * sc0 + bb0; y0 = y0 > 0.f ? y0 : 0.01f * y0;
        float y1 = xv.y * sc1 + bb1; y1 = y1 > 0.f ? y1 : 0.01f * y1;
        int bg = batch[n];
        if (bg != cg) {
            atomicAdd(&p[cg * POOL_F + poff + f], p0);
            atomicAdd(&p[cg * POOL_F + poff + f + 1], p1);
            p0 = p1 = 0.f; cg = bg;
        }
        p0 += y0; p1 += y1;
    }
    atomicAdd(&p[cg * POOL_F + poff + f], p0);
    atomicAdd(&p[cg * POOL_F + poff + f + 1], p1);
}

template<int F>
__global__ void k_bnpool(const __half* __restrict__ x, const float* __restrict__ bnP,
                         const float* __restrict__ g, const float* __restrict__ be,
                         const int* __restrict__ batch, float* __restrict__ p, int poff) {
    bnpool_body<F>(blockIdx.x, x, bnP, g, be, batch, p, poff);
}

// ---------------- MFMA GEMM (transposed D) + fused side work ----------------
// Swapped operands: D = mfma(W_frag, x_frag) -> lane holds 4 consecutive
// FEATURES (kg*4+r) of node (n_base+m*16+col). Vectorized h stores.
// SPLIT: blockIdx.y = head (F/2 features per block).
// SIDE: 0 none, 1 degrank (x>=MBLK), 2 bnpool<K> (x>=MBLK, y==0).

template<int K, int F, bool BNIN, bool SPLIT, typename TIN, typename TOUT, int SIDE>
__global__ void __launch_bounds__(256) k_mfma(
        const TIN* __restrict__ x, const __half* __restrict__ WT,
        const float* __restrict__ bnP,
        const float* __restrict__ g, const float* __restrict__ be,
        const float* __restrict__ a_src, const float* __restrict__ a_dst,
        void* __restrict__ hout, float* __restrict__ al_s, float* __restrict__ al_d,
        const int* __restrict__ dst_raw, int* __restrict__ deg, int* __restrict__ rank,
        const int* __restrict__ batch, float* __restrict__ pp, int poff) {
    if constexpr (SIDE == 1) {
        if (blockIdx.x >= MBLK) { degrank_body(blockIdx.x - MBLK, dst_raw, deg, rank); return; }
    } else if constexpr (SIDE == 2) {
        if (blockIdx.x >= MBLK) {
            if (blockIdx.y == 0)
                bnpool_body<K>(blockIdx.x - MBLK, (const __half*)x, bnP, g, be, batch, pp, poff);
            return;
        }
    }
    constexpr int FH = SPLIT ? F / 2 : F;   // features this block computes
    constexpr int NF = FH / 16;
    constexpr int KS = K / 32;
    constexpr int MT = 2;
    constexpr int C  = F / 2;
    const int hd  = SPLIT ? (int)blockIdx.y : 0;
    const int fof = hd * C;
    __shared__ float scs[K], bbs[K];
    int tid = threadIdx.x;
    if constexpr (BNIN) {
        const float invN = 1.f / (float)N_NODES;
        for (int i = tid; i < K; i += 256) {
            float sm = 0.f, sq = 0.f;
#pragma unroll
            for (int s = 0; s < NSLICE; ++s) {
                sm += bnP[s * 2 * K + i];
                sq += bnP[s * 2 * K + K + i];
            }
            float mean = sm * invN;
            float var  = sq * invN - mean * mean;
            float sc = rsqrtf(var + 1e-5f) * g[i];
            scs[i] = sc;
            bbs[i] = be[i] - mean * sc;
        }
        __syncthreads();
    }
    int wave = tid >> 6, lane = tid & 63;
    int col = lane & 15;
    int kg  = lane >> 4;
    long n_base = ((long)blockIdx.x * 4 + wave) * (MT * 16);
    if (n_base >= N_NODES) return;

    f32x4 acc[MT][NF];
#pragma unroll
    for (int m = 0; m < MT; ++m)
#pragma unroll
        for (int t = 0; t < NF; ++t) acc[m][t] = (f32x4){0.f, 0.f, 0.f, 0.f};

    for (int ks = 0; ks < KS; ++ks) {
        int kb = ks * 32 + kg * 8;
        f16x8 af[MT];
#pragma unroll
        for (int m = 0; m < MT; ++m) {
            long nrow = n_base + m * 16 + col;
            if (nrow >= N_NODES) nrow = N_NODES - 1;   // clamp; result discarded at store
            if constexpr (sizeof(TIN) == 2) {
                uint4 u = *reinterpret_cast<const uint4*>((const __half*)x + nrow * K + kb);
                if constexpr (BNIN) {
                    const __half* hp = reinterpret_cast<const __half*>(&u);
                    f16x8 a;
#pragma unroll
                    for (int j = 0; j < 8; ++j) {
                        float y = __half2float(hp[j]) * scs[kb + j] + bbs[kb + j];
                        y = y > 0.f ? y : 0.01f * y;
                        a[j] = (_Float16)y;
                    }
                    af[m] = a;
                } else {
                    af[m] = *reinterpret_cast<const f16x8*>(&u);
                }
            } else {
                const float* xp = (const float*)x + nrow * K + kb;
                float4 v0 = *reinterpret_cast<const float4*>(xp);
                float4 v1 = *reinterpret_cast<const float4*>(xp + 4);
                f16x8 a;
                a[0] = (_Float16)v0.x; a[1] = (_Float16)v0.y;
                a[2] = (_Float16)v0.z; a[3] = (_Float16)v0.w;
                a[4] = (_Float16)v1.x; a[5] = (_Float16)v1.y;
                a[6] = (_Float16)v1.z; a[7] = (_Float16)v1.w;
                af[m] = a;
            }
        }
#pragma unroll
        for (int t = 0; t < NF; ++t) {
            f16x8 bf = *reinterpret_cast<const f16x8*>(WT + (size_t)(fof + t * 16 + col) * K + kb);
            // swapped: D[feature][node]
            acc[0][t] = __builtin_amdgcn_mfma_f32_16x16x32_f16(bf, af[0], acc[0][t], 0, 0, 0);
            if constexpr (MT > 1)
                acc[1][t] = __builtin_amdgcn_mfma_f32_16x16x32_f16(bf, af[1], acc[1][t], 0, 0, 0);
        }
    }

#pragma unroll
    for (int m = 0; m < MT; ++m) {
        int node_i = (int)(n_base + m * 16 + col);
        bool ok = node_i < N_NODES;
        // vectorized h store: 4 consecutive features per (m,t)
#pragma unroll
        for (int t = 0; t < NF; ++t) {
            int fb = fof + t * 16 + kg * 4;
            if (ok) {
                if constexpr (sizeof(TOUT) == 1) {
                    int pk0 = __builtin_amdgcn_cvt_pk_fp8_f32(acc[m][t][0], acc[m][t][1], 0, false);
                    int pk1 = __builtin_amdgcn_cvt_pk_fp8_f32(acc[m][t][2], acc[m][t][3], 0, false);
                    unsigned u = ((unsigned)pk0 & 0xffffu) | ((unsigned)pk1 << 16);
                    *reinterpret_cast<unsigned*>((unsigned char*)hout + (size_t)node_i * F + fb) = u;
                } else {
                    __half2 p0 = __floats2half2_rn(acc[m][t][0], acc[m][t][1]);
                    __half2 p1 = __floats2half2_rn(acc[m][t][2], acc[m][t][3]);
                    uint2 u;
                    u.x = *reinterpret_cast<unsigned int*>(&p0);
                    u.y = *reinterpret_cast<unsigned int*>(&p1);
                    *reinterpret_cast<uint2*>((__half*)hout + (size_t)node_i * F + fb) = u;
                }
            }
        }
        // al epilogue: per-lane feature partial sums, reduce across kg groups
        if constexpr (SPLIT) {
            float ss = 0.f, sd = 0.f;
#pragma unroll
            for (int t = 0; t < NF; ++t) {
#pragma unroll
                for (int r = 0; r < 4; ++r) {
                    int f = fof + t * 16 + kg * 4 + r;
                    ss += acc[m][t][r] * a_src[f];
                    sd += acc[m][t][r] * a_dst[f];
                }
            }
            ss += __shfl_xor(ss, 16); ss += __shfl_xor(ss, 32);
            sd += __shfl_xor(sd, 16); sd += __shfl_xor(sd, 32);
            if (kg == 0 && ok) {
                al_s[node_i * 2 + hd] = ss;
                al_d[node_i * 2 + hd] = sd;
            }
        } else {
            float ss0 = 0.f, sd0 = 0.f, ss1 = 0.f, sd1 = 0.f;
#pragma unroll
            for (int t = 0; t < NF; ++t) {
#pragma unroll
                for (int r = 0; r < 4; ++r) {
                    int f = t * 16 + kg * 4 + r;
                    float v = acc[m][t][r];
                    if (t < NF / 2) { ss0 += v * a_src[f]; sd0 += v * a_dst[f]; }
                    else            { ss1 += v * a_src[f]; sd1 += v * a_dst[f]; }
                }
            }
            ss0 += __shfl_xor(ss0, 16); ss0 += __shfl_xor(ss0, 32);
            sd0 += __shfl_xor(sd0, 16); sd0 += __shfl_xor(sd0, 32);
            ss1 += __shfl_xor(ss1, 16); ss1 += __shfl_xor(ss1, 32);
            sd1 += __shfl_xor(sd1, 16); sd1 += __shfl_xor(sd1, 32);
            if (kg == 0 && ok) {
                al_s[node_i * 2]     = ss0; al_s[node_i * 2 + 1] = ss1;
                al_d[node_i * 2]     = sd0; al_d[node_i * 2 + 1] = sd1;
            }
        }
    }
}

// ---------------- per-dst gather: masked wide steps + adj prefetch ----------

template<bool FP8> struct PayT;
template<> struct PayT<false> { using T = uint4; };
template<> struct PayT<true>  { using T = uint2; };

template<bool FP8>
__device__ inline void accum8(typename PayT<FP8>::T u, float ee, float acc[8]) {
    if constexpr (FP8) {
        auto f0 = __builtin_amdgcn_cvt_pk_f32_fp8(u.x, false);
        auto f1 = __builtin_amdgcn_cvt_pk_f32_fp8(u.x, true);
        auto f2 = __builtin_amdgcn_cvt_pk_f32_fp8(u.y, false);
        auto f3 = __builtin_amdgcn_cvt_pk_f32_fp8(u.y, true);
        acc[0] += ee * f0[0]; acc[1] += ee * f0[1];
        acc[2] += ee * f1[0]; acc[3] += ee * f1[1];
        acc[4] += ee * f2[0]; acc[5] += ee * f2[1];
        acc[6] += ee * f3[0]; acc[7] += ee * f3[1];
    } else {
        float2 f0 = __half22float2(*reinterpret_cast<const __half2*>(&u.x));
        float2 f1 = __half22float2(*reinterpret_cast<const __half2*>(&u.y));
        float2 f2 = __half22float2(*reinterpret_cast<const __half2*>(&u.z));
        float2 f3 = __half22float2(*reinterpret_cast<const __half2*>(&u.w));
        acc[0] += ee * f0.x; acc[1] += ee * f0.y;
        acc[2] += ee * f1.x; acc[3] += ee * f1.y;
        acc[4] += ee * f2.x; acc[5] += ee * f2.y;
        acc[6] += ee * f3.x; acc[7] += ee * f3.y;
    }
}

template<int F, int C, bool FP8>
__global__ void __launch_bounds__(256) k_gather(
        const int* __restrict__ rowstart, const int* __restrict__ adj,
        const void* __restrict__ hv, const float* __restrict__ al_s,
        const float* __restrict__ al_d, const float* __restrict__ bias,
        __half* __restrict__ xpre) {
    using LT = typename PayT<FP8>::T;
    constexpr int HPL = 8;
    constexpr int LPE = F / HPL;
    constexpr int EPI = 64 / LPE;
    constexpr int UNR = (EPI >= 8) ? 4 : (16 / EPI);
    constexpr int STEP = UNR * EPI;
    constexpr unsigned RSH = FP8 ? 8 : ((F == 64) ? 7 : 8);
    int wave = (blockIdx.x * 256 + threadIdx.x) >> 6;
    int lane = threadIdx.x & 63;
    if (wave >= N_NODES) return;
    int n = wave;
    int rs = rowstart[n], re = rowstart[n + 1];
    float2 aldv = *reinterpret_cast<const float2*>(al_d + n * 2);

    const int es = lane / LPE;
    const int fl = lane % LPE;
    const unsigned fi = fl * HPL;
    const int hd = (fi >= C) ? 1 : 0;
    const float alh = hd ? aldv.y : aldv.x;
    const char* base = (const char*)hv;
    const char* alsb = (const char*)al_s;
    const unsigned fioff = FP8 ? fi : fi * 2;

    float acc[HPL];
#pragma unroll
    for (int j = 0; j < HPL; ++j) acc[j] = 0.f;
    float seh = 0.f;

    int nsteps = (re - rs + STEP - 1) / STEP;
    unsigned sN[UNR];
#pragma unroll
    for (int u = 0; u < UNR; ++u) {
        int e = rs + u * EPI + es;
        sN[u] = (unsigned)adj[min(e, re - 1)];
    }
    for (int t = 0; t < nsteps; ++t) {
        int ibase = rs + t * STEP;
        unsigned sC[UNR];
#pragma unroll
        for (int u = 0; u < UNR; ++u) sC[u] = sN[u];
        if (t + 1 < nsteps) {
            int nb = ibase + STEP;
#pragma unroll
            for (int u = 0; u < UNR; ++u) {
                int e = nb + u * EPI + es;
                sN[u] = (unsigned)adj[min(e, re - 1)];
            }
        }
        float alsN[UNR];
        LT hvN[UNR];
#pragma unroll
        for (int u = 0; u < UNR; ++u) {
            alsN[u] = *reinterpret_cast<const float*>(alsb + ((sC[u] << 3) | (unsigned)(hd << 2)));
            hvN[u] = *reinterpret_cast<const LT*>(base + ((sC[u] << RSH) + fioff));
        }
#pragma unroll
        for (int u = 0; u < UNR; ++u) {
            bool valid = (ibase + u * EPI + es) < re;
            float v = alsN[u] + alh; v = v > 0.f ? v : 0.2f * v;
            v = fminf(v, 80.f);
            float ee = valid ? __expf(v) : 0.f;
            seh += ee;
            accum8<FP8>(hvN[u], ee, acc);
        }
    }

#pragma unroll
    for (int o = LPE; o < 64; o <<= 1) {
        seh += __shfl_xor(seh, o);
#pragma unroll
        for (int j = 0; j < HPL; ++j) acc[j] += __shfl_xor(acc[j], o);
    }

    if (es == 0) {
        float inv = 1.f / (seh + 1e-16f);
        const float* bp = bias + fi;
        __half2 o0 = __floats2half2_rn(acc[0] * inv + bp[0], acc[1] * inv + bp[1]);
        __half2 o1 = __floats2half2_rn(acc[2] * inv + bp[2], acc[3] * inv + bp[3]);
        __half2 o2 = __floats2half2_rn(acc[4] * inv + bp[4], acc[5] * inv + bp[5]);
        __half2 o3 = __floats2half2_rn(acc[6] * inv + bp[6], acc[7] * inv + bp[7]);
        uint4 u;
        u.x = *reinterpret_cast<unsigned int*>(&o0);
        u.y = *reinterpret_cast<unsigned int*>(&o1);
        u.z = *reinterpret_cast<unsigned int*>(&o2);
        u.w = *reinterpret_cast<unsigned int*>(&o3);
        *reinterpret_cast<uint4*>(xpre + (size_t)n * F + fi) = u;
    }
}

// ---------------- BatchNorm stats: 4-slice partials, 480 blocks ------------

template<int F>
__global__ void __launch_bounds__(256) k_bnstats(const __half* __restrict__ x,
        float* __restrict__ bnP) {
    constexpr int SLOTS = F / 8;
    constexpr int RPI   = 256 / SLOTS;
    __shared__ float ls[256][8];
    int tid = threadIdx.x;
    int slot = tid % SLOTS;
    int r0 = tid / SLOTS;
    int slice = blockIdx.x & (NSLICE - 1);
    float s[8], q[8];
#pragma unroll
    for (int j = 0; j < 8; ++j) { s[j] = 0.f; q[j] = 0.f; }
    int stride = gridDim.x * RPI;
    for (int n = blockIdx.x * RPI + r0; n < N_NODES; n += stride) {
        uint4 u = *reinterpret_cast<const uint4*>(x + (size_t)n * F + slot * 8);
        float2 f0 = __half22float2(*reinterpret_cast<__half2*>(&u.x));
        float2 f1 = __half22float2(*reinterpret_cast<__half2*>(&u.y));
        float2 f2 = __half22float2(*reinterpret_cast<__half2*>(&u.z));
        float2 f3 = __half22float2(*reinterpret_cast<__half2*>(&u.w));
        float v[8] = {f0.x, f0.y, f1.x, f1.y, f2.x, f2.y, f3.x, f3.y};
#pragma unroll
        for (int j = 0; j < 8; ++j) { s[j] += v[j]; q[j] += v[j] * v[j]; }
    }
#pragma unroll
    for (int j = 0; j < 8; ++j) ls[tid][j] = s[j];
    __syncthreads();
    if (tid < F) {
        int sl = tid / 8, j = tid % 8;
        float t = 0.f;
        for (int r = 0; r < RPI; ++r) t += ls[r * SLOTS + sl][j];
        atomicAdd(&bnP[slice * 2 * F + tid], t);
    }
    __syncthreads();
#pragma unroll
    for (int j = 0; j < 8; ++j) ls[tid][j] = q[j];
    __syncthreads();
    if (tid < F) {
        int sl = tid / 8, j = tid % 8;
        float t = 0.f;
        for (int r = 0; r < RPI; ++r) t += ls[r * SLOTS + sl][j];
        atomicAdd(&bnP[slice * 2 * F + F + tid], t);
    }
}

// ---------------- final MLP ----------------

__global__ void k_mlp(const float* __restrict__ p, const float* __restrict__ Wc1,
                      const float* __restrict__ bc1, const float* __restrict__ Wc2,
                      const float* __restrict__ bc2, const float* __restrict__ Wc3,
                      const float* __restrict__ bc3, float* __restrict__ out) {
    __shared__ float pr[POOL_F];
    __shared__ float h1[128];
    __shared__ float h2[64];
    int g = blockIdx.x, tid = threadIdx.x;
    for (int i = tid; i < POOL_F; i += 128) pr[i] = p[g * POOL_F + i];
    __syncthreads();
    float a = bc1[tid];
    for (int k = 0; k < POOL_F; ++k) a += pr[k] * Wc1[k * 128 + tid];
    a = a > 0.f ? a : 0.01f * a;
    h1[tid] = a;
    __syncthreads();
    if (tid < 64) {
        float b = bc2[tid];
        for (int k = 0; k < 128; ++k) b += h1[k] * Wc2[k * 64 + tid];
        b = b > 0.f ? b : 0.01f * b;
        h2[tid] = b;
    }
    __syncthreads();
    if (tid < 2) {
        float c = bc3[tid];
        for (int k = 0; k < 64; ++k) c += h2[k] * Wc3[k * 2 + tid];
        out[g * 2 + tid] = c;
    }
}

// ---------------- launch ----------------

extern "C" void kernel_launch(void* const* d_in, const int* in_sizes, int n_in,
                              void* d_out, int out_size, void* d_ws, size_t ws_size,
                              hipStream_t stream) {
    const float* x    = (const float*)d_in[0];
    const int*   ei   = (const int*)d_in[1];
    const int*   batch= (const int*)d_in[3];
    const float* W1  = (const float*)d_in[4];
    const float* as1 = (const float*)d_in[5];
    const float* ad1 = (const float*)d_in[6];
    const float* b1  = (const float*)d_in[7];
    const float* g1  = (const float*)d_in[8];
    const float* be1 = (const float*)d_in[9];
    const float* W2  = (const float*)d_in[10];
    const float* as2 = (const float*)d_in[11];
    const float* ad2 = (const float*)d_in[12];
    const float* b2  = (const float*)d_in[13];
    const float* g2  = (const float*)d_in[14];
    const float* be2 = (const float*)d_in[15];
    const float* W3  = (const float*)d_in[16];
    const float* as3 = (const float*)d_in[17];
    const float* ad3 = (const float*)d_in[18];
    const float* b3  = (const float*)d_in[19];
    const float* g3  = (const float*)d_in[20];
    const float* be3 = (const float*)d_in[21];
    const float* Wc1 = (const float*)d_in[22];
    const float* bc1 = (const float*)d_in[23];
    const float* Wc2 = (const float*)d_in[24];
    const float* bc2 = (const float*)d_in[25];
    const float* Wc3 = (const float*)d_in[26];
    const float* bc3 = (const float*)d_in[27];
    float* out = (float*)d_out;

    char* wsb = (char*)d_ws;
    size_t off = 0;
    auto alloc = [&](size_t b) -> void* {
        void* pp = wsb + off;
        off += (b + 255) & ~(size_t)255;
        return pp;
    };
    int*    adj      = (int*)alloc((size_t)E_TOT * 4);
    int*    rank     = (int*)alloc((size_t)E_TOT * 4);
    int*    rowstart = (int*)alloc((size_t)(N_NODES + 1) * 4);
    int*    deg      = (int*)alloc((size_t)N_NODES * 4);
    int*    bsum     = (int*)alloc(256 * 4);
    float*  al_s     = (float*)alloc((size_t)N_NODES * 2 * 4);
    float*  al_d     = (float*)alloc((size_t)N_NODES * 2 * 4);
    float*  bn1      = (float*)alloc(NSLICE * 512 * 4);
    float*  bn2      = (float*)alloc(NSLICE * 512 * 4);
    float*  bn3      = (float*)alloc(NSLICE * 512 * 4);
    float*  p        = (float*)alloc((size_t)NGRAPH * POOL_F * 4);
    __half* WT1      = (__half*)alloc((size_t)64 * 128 * 2);
    __half* WT2      = (__half*)alloc((size_t)128 * 64 * 2);
    __half* WT3      = (__half*)alloc((size_t)256 * 128 * 2);
    __half* hbuf     = (__half*)alloc((size_t)N_NODES * 128 * 2);   // fp16 payload (layers 1,2)
    unsigned char* h8buf = (unsigned char*)alloc((size_t)N_NODES * 256); // fp8 payload (layer 3)
    __half* xbuf     = (__half*)alloc((size_t)N_NODES * 256 * 2);

    k_init<<<472, 256, 0, stream>>>(deg, p, bn1, W1, W2, W3, WT1, WT2, WT3);

    int wb = (N_NODES + 3) / 4;
    const int sb = 480;

    // ---- layer-1 GEMM (whole F) fused with degrank ----
    k_mfma<128, 64, false, false, float, __half, 1><<<MBLK + EBLK, 256, 0, stream>>>(
        x, WT1, nullptr, nullptr, nullptr, as1, ad1, hbuf, al_s, al_d,
        ei + E_RAW_N, deg, rank, nullptr, nullptr, 0);
    k_scan1<<<SCAN_B, 256, 0, stream>>>(deg, bsum);
    k_scan3<<<SCAN_B, 256, 0, stream>>>(deg, bsum, rowstart);
    k_fill<<<EBLK, 256, 0, stream>>>(ei, rowstart, rank, adj);

    // ---- layer 1 gather/stats ----
    k_gather<64, 32, false><<<wb, 256, 0, stream>>>(rowstart, adj, hbuf, al_s, al_d, b1, xbuf);
    k_bnstats<64><<<sb, 256, 0, stream>>>(xbuf, bn1);

    // ---- layer 2 GEMM (F split over y) fused with bnpool1 ----
    k_mfma<64, 128, true, true, __half, __half, 2><<<dim3(MBLK + PBLK, 2), 256, 0, stream>>>(
        xbuf, WT2, bn1, g1, be1, as2, ad2, hbuf, al_s, al_d,
        nullptr, nullptr, nullptr, batch, p, 0);
    k_gather<128, 64, false><<<wb, 256, 0, stream>>>(rowstart, adj, hbuf, al_s, al_d, b2, xbuf);
    k_bnstats<128><<<sb, 256, 0, stream>>>(xbuf, bn2);

    // ---- layer 3 GEMM (F split over y) fused with bnpool2 ----
    k_mfma<128, 256, true, true, __half, unsigned char, 2><<<dim3(MBLK + PBLK, 2), 256, 0, stream>>>(
        xbuf, WT3, bn2, g2, be2, as3, ad3, h8buf, al_s, al_d,
        nullptr, nullptr, nullptr, batch, p, 64);
    k_gather<256, 128, true><<<wb, 256, 0, stream>>>(rowstart, adj, h8buf, al_s, al_d, b3, xbuf);
    k_bnstats<256><<<sb, 256, 0, stream>>>(xbuf, bn3);

    // ---- bnpool3 + readout MLP ----
    k_bnpool<256><<<PBLK, 256, 0, stream>>>(xbuf, bn3, g3, be3, batch, p, 192);
    k_mlp<<<NGRAPH, 128, 0, stream>>>(p, Wc1, bc1, Wc2, bc2, Wc3, bc3, out);
}